// Round 1
// baseline (283.385 us; speedup 1.0000x reference)
//
#include <hip/hip_runtime.h>

typedef float f32x4  __attribute__((ext_vector_type(4)));
typedef float f32x16 __attribute__((ext_vector_type(16)));
typedef short s16x8  __attribute__((ext_vector_type(8)));
typedef unsigned short u16;

#define LL 2048
#define DD 64
#define NITER 32
#define SC_OFF 4194304ull

struct SMem {
    u16   Khi[64][72];           // key tile, bf16, padded stride 72 (144B, bank-balanced)
    u16   VT [64][72];           // V^T tile (d rows, c cols), bf16
    float bias[64];              // -1e9 * mask per key of this tile
    union {
        u16 Q[128][72];          // prologue-only staging for Q hi/lo
        unsigned char P[4][4096];// P^T repack: [iw][ (j*128 + quad*8) ^ ((j&7)<<4) ]
    } u;
};

__device__ __forceinline__ u16 bf16_rne(float x) {
    unsigned u = __builtin_bit_cast(unsigned, x);
    return (u16)((u + 0x7FFFu + ((u >> 16) & 1u)) >> 16);
}
__device__ __forceinline__ float bf16f(u16 h) {
    unsigned u = (unsigned)h << 16;
    return __builtin_bit_cast(float, u);
}

__global__ __launch_bounds__(512, 4)
void psam_kernel(const float* __restrict__ Qg0, const float* __restrict__ Kg0,
                 const float* __restrict__ Vg0, const int* __restrict__ Mg0,
                 float* __restrict__ out)
{
    __shared__ SMem sm;
    const int tid = threadIdx.x;
    const int w = tid >> 6, l = tid & 63;
    const int j31 = l & 31, h = l >> 5;   // lane col within 32, half-wave
    const int cw = w & 1, iw = w >> 1;    // c-half (S) / d-half (PV), i-chunk of 32

    // XCD-aware swizzle: 512 blocks, 64 per XCD -> all 16 blocks of a (b,h) share one L2
    const int bid = ((int)blockIdx.x & 7) * 64 + ((int)blockIdx.x >> 3);
    const int bh = bid >> 4;
    const int m0 = (bid & 15) << 7;       // q-row tile start
    const int bB = bh >> 4;               // batch index (H=16)

    const float* Qg = Qg0 + ((size_t)bh * LL + m0) * DD;
    const float* Kg = Kg0 + (size_t)bh * LL * DD;
    const float* Vg = Vg0 + (size_t)bh * LL * DD;
    const int*   Mg = Mg0 + (size_t)bB * LL;
    float* So = out + SC_OFF + (size_t)bh * LL * LL + (size_t)m0 * LL;
    float* Oo = out + ((size_t)bh * LL + m0) * DD;

    // ---------- prologue: stage Q, load resident hi/lo B-fragments ----------
    const int qi = tid >> 2, qd = (tid & 3) * 16;
    f32x4 qv[4];
    {
        const f32x4* s = (const f32x4*)(Qg + qi * DD + qd);
        qv[0] = s[0]; qv[1] = s[1]; qv[2] = s[2]; qv[3] = s[3];
    }
    u16 qhi[16];
#pragma unroll
    for (int e = 0; e < 16; ++e) qhi[e] = bf16_rne(qv[e >> 2][e & 3]);
    {
        s16x8 a, b;
#pragma unroll
        for (int i = 0; i < 8; ++i) { a[i] = (short)qhi[i]; b[i] = (short)qhi[8 + i]; }
        *(s16x8*)&sm.u.Q[qi][qd] = a;
        *(s16x8*)&sm.u.Q[qi][qd + 8] = b;
    }
    __syncthreads();
    s16x8 qfh[4], qfl[4];
#pragma unroll
    for (int ks = 0; ks < 4; ++ks)
        qfh[ks] = *(const s16x8*)&sm.u.Q[iw * 32 + j31][ks * 16 + h * 8];
    __syncthreads();
    {
        s16x8 a, b;
#pragma unroll
        for (int i = 0; i < 8; ++i) {
            a[i] = (short)bf16_rne(qv[i >> 2][i & 3] - bf16f(qhi[i]));
            b[i] = (short)bf16_rne(qv[(8 + i) >> 2][(8 + i) & 3] - bf16f(qhi[8 + i]));
        }
        *(s16x8*)&sm.u.Q[qi][qd] = a;
        *(s16x8*)&sm.u.Q[qi][qd + 8] = b;
    }
    __syncthreads();
#pragma unroll
    for (int ks = 0; ks < 4; ++ks)
        qfl[ks] = *(const s16x8*)&sm.u.Q[iw * 32 + j31][ks * 16 + h * 8];

    f32x16 accO;
#pragma unroll
    for (int e = 0; e < 16; ++e) accO[e] = 0.0f;

    const int kc = tid >> 3, kd = (tid & 7) * 8;     // K staging: row, col base
    const int vc = tid & 63, vd = (tid >> 6) * 8;    // V staging: row, col base
    unsigned char* spw = &sm.u.P[iw][0];
    const int swz = (j31 & 7) << 4;

    for (int t = 0; t < NITER; ++t) {
        const int j0 = t * 64;
        __syncthreads();   // previous iteration done reading Khi/VT/P

        // ---- stage K tile (bf16), coalesced full-row loads ----
        {
            const f32x4* s = (const f32x4*)(Kg + (size_t)(j0 + kc) * DD + kd);
            f32x4 x = s[0], y = s[1];
            s16x8 kv;
#pragma unroll
            for (int i = 0; i < 4; ++i) { kv[i] = (short)bf16_rne(x[i]); kv[4 + i] = (short)bf16_rne(y[i]); }
            *(s16x8*)&sm.Khi[kc][kd] = kv;
        }
        // ---- stage V^T (bf16), conflict-free b16 writes (lane -> consecutive c) ----
        {
            const f32x4* s = (const f32x4*)(Vg + (size_t)(j0 + vc) * DD + vd);
            f32x4 x = s[0], y = s[1];
#pragma unroll
            for (int i = 0; i < 4; ++i) {
                sm.VT[vd + i][vc]     = bf16_rne(x[i]);
                sm.VT[vd + 4 + i][vc] = bf16_rne(y[i]);
            }
        }
        if (tid < 64) sm.bias[tid] = -1.0e9f * (float)Mg[j0 + tid];
        __syncthreads();

        // ---- S^T = K * Q^T  (wave: c-half cw, i-chunk iw), Q split hi+lo ----
        f32x16 accS;
#pragma unroll
        for (int e = 0; e < 16; ++e) accS[e] = 0.0f;
#pragma unroll
        for (int ks = 0; ks < 4; ++ks) {
            s16x8 kf = *(const s16x8*)&sm.Khi[cw * 32 + j31][ks * 16 + h * 8];
            accS = __builtin_amdgcn_mfma_f32_32x32x16_bf16(kf, qfh[ks], accS, 0, 0, 0);
            accS = __builtin_amdgcn_mfma_f32_32x32x16_bf16(kf, qfl[ks], accS, 0, 0, 0);
        }
        // C/D layout: col(i)=lane&31, row(c)=(reg&3)+8*(reg>>2)+4*(lane>>5)
        float* srow = So + (size_t)(iw * 32 + j31) * LL + j0 + cw * 32 + h * 4;
#pragma unroll
        for (int g = 0; g < 4; ++g) {
            f32x4 b4 = *(const f32x4*)&sm.bias[cw * 32 + h * 4 + g * 8];
            f32x4 p;
#pragma unroll
            for (int r = 0; r < 4; ++r) {
                float x  = accS[g * 4 + r] * 0.125f + b4[r];          // qk/8 + mask*(-1e9)
                float tt = __builtin_amdgcn_exp2f(x * 1.44269504f);   // e^x
                p[r] = __builtin_amdgcn_logf(1.0f + tt) * 3.38450771757785852e-4f; // ln(1+e^x)/2048
            }
            *(f32x4*)(srow + g * 8) = p;                              // coalesced scores store
            // repack P^T quad (4 consecutive c at fixed i) -> one b64, XOR-swizzled
            unsigned lo32 = (unsigned)bf16_rne(p[0]) | ((unsigned)bf16_rne(p[1]) << 16);
            unsigned hi32 = (unsigned)bf16_rne(p[2]) | ((unsigned)bf16_rne(p[3]) << 16);
            unsigned long long pk = (unsigned long long)lo32 | ((unsigned long long)hi32 << 32);
            *(unsigned long long*)(spw + ((j31 * 128 + (cw * 8 + g * 2 + h) * 8) ^ swz)) = pk;
        }
        __syncthreads();   // P from both c-half waves visible

        // ---- OUT^T += V^T * P^T  (wave: d-half cw, i-chunk iw) ----
#pragma unroll
        for (int ks = 0; ks < 4; ++ks) {
            s16x8 va = *(const s16x8*)&sm.VT[cw * 32 + j31][ks * 16 + h * 8];
            s16x8 pb = *(const s16x8*)(spw + ((j31 * 128 + (ks * 4 + h * 2) * 8) ^ swz));
            accO = __builtin_amdgcn_mfma_f32_32x32x16_bf16(va, pb, accO, 0, 0, 0);
        }
    }

    // ---- epilogue: store OUT (lane holds row i = iw*32+j31, 16 d-values) ----
#pragma unroll
    for (int g = 0; g < 4; ++g) {
        f32x4 o;
#pragma unroll
        for (int r = 0; r < 4; ++r) o[r] = accO[g * 4 + r];
        *(f32x4*)(Oo + (size_t)(iw * 32 + j31) * DD + cw * 32 + h * 4 + g * 8) = o;
    }
}

extern "C" void kernel_launch(void* const* d_in, const int* in_sizes, int n_in,
                              void* d_out, int out_size, void* d_ws, size_t ws_size,
                              hipStream_t stream) {
    const float* q    = (const float*)d_in[0];
    const float* k    = (const float*)d_in[1];
    const float* v    = (const float*)d_in[2];
    const int*   mask = (const int*)d_in[5];   // p_q (3), p_k (4) unused by reference
    float* out = (float*)d_out;
    hipLaunchKernelGGL(psam_kernel, dim3(512), dim3(512), 0, stream, q, k, v, mask, out);
}

// Round 2
// 154.737 us; speedup vs baseline: 1.8314x; 1.8314x over previous
//
#include <hip/hip_runtime.h>

typedef float f32x4  __attribute__((ext_vector_type(4)));
typedef float f32x16 __attribute__((ext_vector_type(16)));
typedef short s16x8  __attribute__((ext_vector_type(8)));
typedef unsigned short u16;

#define LL 2048
#define DD 64
#define NITER 32
#define SC_OFF 4194304ull

struct SMem {
    u16   Khi[64][72];           // key tile, bf16, padded stride 144B (bank-balanced)
    u16   VT [64][72];           // V^T tile (d rows, c cols), bf16
    float bias[64];              // -1e9 * mask per key of this tile
    union {
        u16 Q[128][72];          // prologue-only staging for Q hi/lo
        unsigned char P[4][4096];// per-iw P tile [i 0..31][c 0..63] bf16, XOR-swizzled rows
    } u;
};

__device__ __forceinline__ u16 bf16_rne(float x) {
    unsigned u = __builtin_bit_cast(unsigned, x);
    return (u16)((u + 0x7FFFu + ((u >> 16) & 1u)) >> 16);
}
__device__ __forceinline__ float bf16f(u16 h) {
    unsigned u = (unsigned)h << 16;
    return __builtin_bit_cast(float, u);
}

__global__ __launch_bounds__(512, 4)
void psam_kernel(const float* __restrict__ Qg0, const float* __restrict__ Kg0,
                 const float* __restrict__ Vg0, const int* __restrict__ Mg0,
                 float* __restrict__ out)
{
    __shared__ SMem sm;
    const int tid = threadIdx.x;
    const int w = tid >> 6, l = tid & 63;
    const int j31 = l & 31, h = l >> 5;   // lane index within 32, half-wave
    const int cw = w & 1, iw = w >> 1;    // key-half / d-half, query chunk of 32

    // XCD-aware swizzle: 512 blocks, 64 per XCD -> all 16 blocks of a (b,h) share one L2
    const int bid = ((int)blockIdx.x & 7) * 64 + ((int)blockIdx.x >> 3);
    const int bh = bid >> 4;
    const int m0 = (bid & 15) << 7;       // q-row tile start
    const int bB = bh >> 4;               // batch index (H=16)

    const float* Qg = Qg0 + ((size_t)bh * LL + m0) * DD;
    const float* Kg = Kg0 + (size_t)bh * LL * DD;
    const float* Vg = Vg0 + (size_t)bh * LL * DD;
    const int*   Mg = Mg0 + (size_t)bB * LL;
    float* So = out + SC_OFF + (size_t)bh * LL * LL + (size_t)m0 * LL;
    float* Oo = out + ((size_t)bh * LL + m0) * DD;

    // ---------- prologue: stage Q, load resident hi/lo A-fragments ----------
    const int qi = tid >> 2, qd = (tid & 3) * 16;
    f32x4 qv[4];
    {
        const f32x4* s = (const f32x4*)(Qg + qi * DD + qd);
        qv[0] = s[0]; qv[1] = s[1]; qv[2] = s[2]; qv[3] = s[3];
    }
    u16 qhi[16];
#pragma unroll
    for (int e = 0; e < 16; ++e) qhi[e] = bf16_rne(qv[e >> 2][e & 3]);
    {
        s16x8 a, b;
#pragma unroll
        for (int i = 0; i < 8; ++i) { a[i] = (short)qhi[i]; b[i] = (short)qhi[8 + i]; }
        *(s16x8*)&sm.u.Q[qi][qd] = a;
        *(s16x8*)&sm.u.Q[qi][qd + 8] = b;
    }
    __syncthreads();
    s16x8 qfh[4], qfl[4];
#pragma unroll
    for (int ks = 0; ks < 4; ++ks)
        qfh[ks] = *(const s16x8*)&sm.u.Q[iw * 32 + j31][ks * 16 + h * 8];
    __syncthreads();
    {
        s16x8 a, b;
#pragma unroll
        for (int i = 0; i < 8; ++i) {
            a[i] = (short)bf16_rne(qv[i >> 2][i & 3] - bf16f(qhi[i]));
            b[i] = (short)bf16_rne(qv[(8 + i) >> 2][(8 + i) & 3] - bf16f(qhi[8 + i]));
        }
        *(s16x8*)&sm.u.Q[qi][qd] = a;
        *(s16x8*)&sm.u.Q[qi][qd + 8] = b;
    }
    __syncthreads();
#pragma unroll
    for (int ks = 0; ks < 4; ++ks)
        qfl[ks] = *(const s16x8*)&sm.u.Q[iw * 32 + j31][ks * 16 + h * 8];

    f32x16 accO;
#pragma unroll
    for (int e = 0; e < 16; ++e) accO[e] = 0.0f;

    const int kc = tid >> 3, kd = (tid & 7) * 8;     // K staging: row, col base
    const int vc = tid & 63, vd = (tid >> 6) * 8;    // V staging: row, col base
    unsigned char* spw = &sm.u.P[iw][0];
    const int colb = (cw * 32 + j31) * 2;            // P column byte offset for this lane

    for (int t = 0; t < NITER; ++t) {
        const int j0 = t * 64;
        __syncthreads();   // previous iteration done reading Khi/VT/P

        // ---- stage K tile (bf16), coalesced full-row loads ----
        {
            const f32x4* s = (const f32x4*)(Kg + (size_t)(j0 + kc) * DD + kd);
            f32x4 x = s[0], y = s[1];
            s16x8 kv;
#pragma unroll
            for (int i = 0; i < 4; ++i) { kv[i] = (short)bf16_rne(x[i]); kv[4 + i] = (short)bf16_rne(y[i]); }
            *(s16x8*)&sm.Khi[kc][kd] = kv;
        }
        // ---- stage V^T (bf16), conflict-free b16 writes ----
        {
            const f32x4* s = (const f32x4*)(Vg + (size_t)(j0 + vc) * DD + vd);
            f32x4 x = s[0], y = s[1];
#pragma unroll
            for (int i = 0; i < 4; ++i) {
                sm.VT[vd + i][vc]     = bf16_rne(x[i]);
                sm.VT[vd + 4 + i][vc] = bf16_rne(y[i]);
            }
        }
        if (tid < 64) sm.bias[tid] = -1.0e9f * (float)Mg[j0 + tid];
        __syncthreads();

        // ---- S = Q * K^T  (A=Q frags, B=K frags -> col=lane=key) ----
        f32x16 accS;
#pragma unroll
        for (int e = 0; e < 16; ++e) accS[e] = 0.0f;
#pragma unroll
        for (int ks = 0; ks < 4; ++ks) {
            s16x8 kf = *(const s16x8*)&sm.Khi[cw * 32 + j31][ks * 16 + h * 8];
            accS = __builtin_amdgcn_mfma_f32_32x32x16_bf16(qfh[ks], kf, accS, 0, 0, 0);
            accS = __builtin_amdgcn_mfma_f32_32x32x16_bf16(qfl[ks], kf, accS, 0, 0, 0);
        }
        // C/D layout: col(key c)=lane&31, row(query i)=(reg&3)+8*(reg>>2)+4*(lane>>5)
        const float bl = sm.bias[cw * 32 + j31];
        float* sp = So + (size_t)(iw * 32 + 4 * h) * LL + j0 + cw * 32 + j31;
#pragma unroll
        for (int g = 0; g < 4; ++g) {
#pragma unroll
            for (int r = 0; r < 4; ++r) {
                float x  = accS[g * 4 + r] * 0.125f + bl;              // qk/8 + mask*(-1e9)
                float tt = __builtin_amdgcn_exp2f(x * 1.44269504f);    // e^x
                float p  = __builtin_amdgcn_logf(1.0f + tt) * 3.38450771757785852e-4f;
                __builtin_nontemporal_store(p, sp + (size_t)(8 * g + r) * LL);  // dense 256B/inst
                const int il = 8 * g + 4 * h + r;                      // local query row
                *(u16*)(spw + ((il * 128 + colb) ^ ((il & 7) << 4))) = bf16_rne(p);
            }
        }
        __syncthreads();   // P from both key-half waves visible

        // ---- OUT^T += V^T * P^T  (wave: d-half cw, i-chunk iw) ----
#pragma unroll
        for (int ks = 0; ks < 4; ++ks) {
            s16x8 va = *(const s16x8*)&sm.VT[cw * 32 + j31][ks * 16 + h * 8];
            s16x8 pb = *(const s16x8*)(spw + ((j31 * 128 + ks * 32 + h * 16) ^ ((j31 & 7) << 4)));
            accO = __builtin_amdgcn_mfma_f32_32x32x16_bf16(va, pb, accO, 0, 0, 0);
        }
    }

    // ---- epilogue: store OUT (lane holds row i = iw*32+j31, 16 d-values) ----
#pragma unroll
    for (int g = 0; g < 4; ++g) {
        f32x4 o;
#pragma unroll
        for (int r = 0; r < 4; ++r) o[r] = accO[g * 4 + r];
        *(f32x4*)(Oo + (size_t)(iw * 32 + j31) * DD + cw * 32 + h * 4 + g * 8) = o;
    }
}

extern "C" void kernel_launch(void* const* d_in, const int* in_sizes, int n_in,
                              void* d_out, int out_size, void* d_ws, size_t ws_size,
                              hipStream_t stream) {
    const float* q    = (const float*)d_in[0];
    const float* k    = (const float*)d_in[1];
    const float* v    = (const float*)d_in[2];
    const int*   mask = (const int*)d_in[5];   // p_q, p_k unused by reference
    float* out = (float*)d_out;
    hipLaunchKernelGGL(psam_kernel, dim3(512), dim3(512), 0, stream, q, k, v, mask, out);
}